// Round 9
// baseline (342.139 us; speedup 1.0000x reference)
//
#include <hip/hip_runtime.h>

#define TOKENS 8192
#define D_IN   4096
#define D_OUT  4096

typedef _Float16 f16;
typedef __attribute__((ext_vector_type(8))) _Float16 half8;
typedef __attribute__((ext_vector_type(4))) float    f32x4;
typedef __attribute__((address_space(3))) char       lds_char;

// ---------------- conversion kernels ----------------

__global__ void cvt_x_kernel(const float* __restrict__ x, f16* __restrict__ xh) {
    size_t i = ((size_t)blockIdx.x * blockDim.x + threadIdx.x) * 4;
    float4 v = *reinterpret_cast<const float4*>(x + i);
    union { f16 h[4]; uint2 u; } p;
    p.h[0] = (f16)v.x; p.h[1] = (f16)v.y; p.h[2] = (f16)v.z; p.h[3] = (f16)v.w;
    *reinterpret_cast<uint2*>(xh + i) = p.u;
}

__global__ void cvt_w_kernel(const int* __restrict__ w, f16* __restrict__ wh,
                             const float* __restrict__ scale_p,
                             const int* __restrict__ zp_p) {
    size_t i = ((size_t)blockIdx.x * blockDim.x + threadIdx.x) * 4;
    float s = scale_p[0];
    float z = (float)zp_p[0];
    int4 v = *reinterpret_cast<const int4*>(w + i);
    union { f16 h[4]; uint2 u; } p;
    p.h[0] = (f16)(((float)v.x - z) * s);
    p.h[1] = (f16)(((float)v.y - z) * s);
    p.h[2] = (f16)(((float)v.z - z) * s);
    p.h[3] = (f16)(((float)v.w - z) * s);
    *reinterpret_cast<uint2*>(wh + i) = p.u;
}

// ---------------- GEMM: 256x128 tile, BK=32, 8 waves, 2 BLOCKS/CU ---------
// R9 post-mortem of R3..R8: five intra-block schedules all 269-290us,
// MfmaUtil 43-48% -- with 256 regs/wave (128 VGPR + 128 acc) only 1 block/CU
// fits; 8 lockstep waves leave the MFMA pipe empty at every wait. LEVER:
// occupancy. 64x64 per-wave output -> acc 64 regs, total ~115/wave <= 128
// -> 16 waves/CU (2 blocks). Block A's drains hide under block B's MFMA
// (m114 co-scheduling), replacing all the manual pipelining.
//
// LDS: 2 dbuf x (A 16KB + B 8KB) = 48KB/block (2 blocks = 96KB <= 160).
// Rows are 64B (BK=32 f16), 4 slots of 16B; swizzle phys_slot =
// slot ^ ((row>>1)&3) (even 8-lane-per-4-bank spread = conflict-free).
// global_load_lds writes linearly -> swizzle pre-applied to the per-lane
// GLOBAL source column (rule 21); ds_read applies the same XOR.
//
// Loop (simple 2-phase; TLP does the hiding):
//   stage A(t+1) x2 + B(t+1) x1 into buf^1
//   read a[4],b[4] (8 x ds_read_b128, base + fm*1024 imm offsets)
//   16 MFMA
//   lgkm0 (reads retired before BAR: WAR vs next iter's DMA into this buf)
//   vmcnt(0) (t+1 resident); BAR
// Last tile peeled (no stage/bar). Protocol (R5 lesson) holds: drain ->
// barrier -> read at the single consume point per iter.

#define BM 256
#define BN 128
#define BK 32
#define NT (D_IN / BK)      // 128 K-tiles
#define LDS_BUF   24576     // A 16384 + B 8192
#define LDS_B_OFF 16384

__device__ __forceinline__ void stage16(const f16* g, lds_char* l) {
    __builtin_amdgcn_global_load_lds(
        (const __attribute__((address_space(1))) void*)g,
        (__attribute__((address_space(3))) void*)l, 16, 0, 0);
}

#define LDS_LOAD8(p) (*(const __attribute__((address_space(3))) half8*)(p))

#define BAR()      __builtin_amdgcn_s_barrier()
#define LGKM0()    asm volatile("s_waitcnt lgkmcnt(0)" ::: "memory")
#define VMCNT0()   asm volatile("s_waitcnt vmcnt(0)" ::: "memory")
#define PRIO(x)    __builtin_amdgcn_s_setprio(x)

__global__ __launch_bounds__(512, 4)   // cap 128 regs/wave -> 2 blocks/CU
void gemm_occ(const f16* __restrict__ A, const f16* __restrict__ B,
              const float* __restrict__ bias,
              const float* __restrict__ oscale_p, const int* __restrict__ ozp_p,
              float* __restrict__ C)
{
    __shared__ __align__(1024) char smem_[2 * LDS_BUF];   // 48 KiB
    lds_char* smem = (lds_char*)smem_;
    constexpr int K = D_IN, N = D_OUT;

    // XCD-aware bijective swizzle (grid = 1024, divisible by 8)
    int nwg = gridDim.x;
    int cpx = nwg >> 3;
    int bid = blockIdx.x;
    int swz = (bid & 7) * cpx + (bid >> 3);
    int ntn = N / BN;                        // 32
    int m0 = (swz / ntn) * BM;
    int n0 = (swz % ntn) * BN;

    int tid = threadIdx.x;
    int l   = tid & 63;
    int wv  = tid >> 6;                      // 0..7
    int wr  = wv >> 1;                       // 0..3 (M)
    int wc  = wv & 1;                        // 0..1 (N)
    int lr  = l & 15;

    // ---- staging geometry: one block-wide stage16 = 8KB = 128 rows x 64B.
    // lane l -> row = wv*16 + (l>>2), phys slot = l&3;
    // pre-swizzled global col = ((l&3) ^ ((row>>1)&3)) * 8 f16.
    // (+128 rows leaves (row>>1)&3 unchanged, so A's 2nd call shares scol.)
    int srow = wv * 16 + (l >> 2);
    int scol = ((l & 3) ^ ((srow >> 1) & 3)) * 8;
    const f16* gA = A + (size_t)(m0 + srow) * K + scol;
    const f16* gB = B + (size_t)(n0 + srow) * K + scol;
    lds_char* dstbase = smem + wv * 1024 + l * 16;

    // ---- read offsets (loop-invariant; fm/fn become imm offsets):
    // row rr = w*64 + fm*16 + lr  ->  (rr>>1)&3 == (lr>>1)&3  (fm,w drop out)
    int colsel = ((l >> 4) ^ ((lr >> 1) & 3)) << 4;
    int aoff = (wr * 64 + lr) * 64 + colsel;
    int boff = LDS_B_OFF + (wc * 64 + lr) * 64 + colsel;

    f32x4 acc[4][4] = {};
    half8 a[4], b[4];

    // ---- prologue: stage tile 0 -> buf0, drain, barrier
    stage16(gA,                    dstbase);
    stage16(gA + (size_t)128 * K,  dstbase + 8192);
    stage16(gB,                    dstbase + LDS_B_OFF);
    VMCNT0();
    BAR();

    for (int t = 0; t < NT - 1; ++t) {
        const lds_char* bufr = smem + (t & 1) * LDS_BUF;
        lds_char* dstw = dstbase + ((t + 1) & 1) * LDS_BUF;
        const f16* nA = gA + (size_t)(t + 1) * BK;
        const f16* nB = gB + (size_t)(t + 1) * BK;

        stage16(nA,                   dstw);
        stage16(nA + (size_t)128 * K, dstw + 8192);
        stage16(nB,                   dstw + LDS_B_OFF);

        #pragma unroll
        for (int fm = 0; fm < 4; ++fm) a[fm] = LDS_LOAD8(bufr + aoff + fm * 1024);
        #pragma unroll
        for (int fn = 0; fn < 4; ++fn) b[fn] = LDS_LOAD8(bufr + boff + fn * 1024);

        PRIO(1);
        #pragma unroll
        for (int fm = 0; fm < 4; ++fm)
            #pragma unroll
            for (int fn = 0; fn < 4; ++fn)
                acc[fm][fn] = __builtin_amdgcn_mfma_f32_16x16x32_f16(
                    a[fm], b[fn], acc[fm][fn], 0, 0, 0);
        PRIO(0);

        LGKM0();     // reads of bufr retired before BAR (WAR vs next DMA)
        VMCNT0();    // tile t+1 resident
        BAR();
    }

    // ---- peeled last tile: no staging, buffer already drained
    {
        const lds_char* bufr = smem + ((NT - 1) & 1) * LDS_BUF;
        #pragma unroll
        for (int fm = 0; fm < 4; ++fm) a[fm] = LDS_LOAD8(bufr + aoff + fm * 1024);
        #pragma unroll
        for (int fn = 0; fn < 4; ++fn) b[fn] = LDS_LOAD8(bufr + boff + fn * 1024);
        PRIO(1);
        #pragma unroll
        for (int fm = 0; fm < 4; ++fm)
            #pragma unroll
            for (int fn = 0; fn < 4; ++fn)
                acc[fm][fn] = __builtin_amdgcn_mfma_f32_16x16x32_f16(
                    a[fm], b[fn], acc[fm][fn], 0, 0, 0);
        PRIO(0);
    }

    // ---- epilogue: bias + fake-quantize (round-half-even = jnp.round)
    float os  = oscale_p[0];
    float ozp = (float)ozp_p[0];
    float inv = 1.0f / os;
    #pragma unroll
    for (int fm = 0; fm < 4; ++fm) {
        int rowb = m0 + wr * 64 + fm * 16 + (l >> 4) * 4;
        #pragma unroll
        for (int fn = 0; fn < 4; ++fn) {
            int col = n0 + wc * 64 + fn * 16 + lr;
            float bv = bias[col];
            f32x4 v = acc[fm][fn];
            #pragma unroll
            for (int j = 0; j < 4; ++j) {
                float o = v[j] + bv;
                float q = rintf(o * inv) + ozp;
                q = fminf(fmaxf(q, 0.0f), 255.0f);
                C[(size_t)(rowb + j) * N + col] = (q - ozp) * os;
            }
        }
    }
}

// ---------------- launch ----------------

extern "C" void kernel_launch(void* const* d_in, const int* in_sizes, int n_in,
                              void* d_out, int out_size, void* d_ws, size_t ws_size,
                              hipStream_t stream) {
    const float* x      = (const float*)d_in[0];
    const int*   w8     = (const int*)d_in[1];
    const float* wscale = (const float*)d_in[2];
    const int*   wzp    = (const int*)d_in[3];
    const float* bias   = (const float*)d_in[4];
    const float* oscale = (const float*)d_in[5];
    const int*   ozp    = (const int*)d_in[6];
    float* out = (float*)d_out;

    const size_t x_elems = (size_t)TOKENS * D_IN;
    const size_t w_elems = (size_t)D_OUT * D_IN;
    const size_t need = (x_elems + w_elems) * sizeof(f16);
    if (ws_size < need) return;

    f16* xh = (f16*)d_ws;
    f16* wh = xh + x_elems;

    {
        int blocks = (int)(x_elems / 4 / 256);
        cvt_x_kernel<<<blocks, 256, 0, stream>>>(x, xh);
    }
    {
        int blocks = (int)(w_elems / 4 / 256);
        cvt_w_kernel<<<blocks, 256, 0, stream>>>(w8, wh, wscale, wzp);
    }
    {
        int grid = (TOKENS / BM) * (D_OUT / BN);   // 32 * 32 = 1024, %8 == 0
        gemm_occ<<<grid, 512, 0, stream>>>(xh, wh, bias, oscale, ozp, out);
    }
}